// Round 20
// baseline (374.296 us; speedup 1.0000x reference)
//
#include <hip/hip_runtime.h>
#include <stdint.h>

#define T_TOK 4096
#define DDIM  1024
#define HDIM  4096
#define NEXP  8
#define MAXTILES 72                     // ceil(8192/128) + 8 experts of padding
#define G1_NWG (MAXTILES*(HDIM/128))    // 2304 GEMM1 blocks
#define TW_NWG 8192                     // transpose blocks: (K/64)*(N/64)*E

typedef short s16x8  __attribute__((ext_vector_type(8)));
typedef float f32x4t __attribute__((ext_vector_type(4)));

#define GLOAD16(gp, lp) __builtin_amdgcn_global_load_lds( \
    (const __attribute__((address_space(1))) unsigned int*)(gp), \
    (__attribute__((address_space(3))) unsigned int*)(lp), 16, 0, 0)
#define SB0 __builtin_amdgcn_sched_barrier(0)

__device__ __forceinline__ unsigned short f2b(float f){
  unsigned int u = __float_as_uint(f);
  u += 0x7fffu + ((u >> 16) & 1u);   // RNE
  return (unsigned short)(u >> 16);
}

// BK=32 rows are 64 B (4 x 16B slots). Swizzle: slot ^= (row>>1)&3 (verified involution pair).
__device__ __forceinline__ s16x8 lds_frag(const unsigned short* base, int row, int colElem){
  int byte = row*64 + ((colElem*2) ^ (((row >> 1) & 3) << 4));
  return *(const s16x8*)((const char*)base + byte);
}

// ---------------- transpose body: W [K][N] fp32 -> Wt [N][K] bf16, one 64x64 tile ----
__device__ __forceinline__ void transpose_body(const float* __restrict__ W,
                                               unsigned short* __restrict__ Wt,
                                               int K, int N, int bid, int tid,
                                               unsigned short (*t)[72]){
  const int nb = N >> 6, kb = K >> 6;
  const int n0 = (bid % nb) * 64;
  const int k0 = ((bid / nb) % kb) * 64;
  const int e  = bid / (nb * kb);
  const float* Wb = W + (size_t)e*K*N;
  unsigned short* Wtb = Wt + (size_t)e*K*N;
  const int r  = tid >> 4;
  const int c4 = (tid & 15) * 4;
  #pragma unroll
  for (int i = 0; i < 4; ++i){
    int k = r + i*16;
    float4 v = *(const float4*)(Wb + (size_t)(k0+k)*N + n0 + c4);
    t[c4+0][k] = f2b(v.x); t[c4+1][k] = f2b(v.y);
    t[c4+2][k] = f2b(v.z); t[c4+3][k] = f2b(v.w);
  }
  __syncthreads();
  const int kk = (tid & 7) * 8;
  #pragma unroll
  for (int i = 0; i < 2; ++i){
    int n = (tid >> 3) + i*32;
    s16x8 v;
    #pragma unroll
    for (int j = 0; j < 8; ++j) v[j] = (short)t[n][kk+j];
    *(s16x8*)(Wtb + (size_t)(n0+n)*K + k0 + kk) = v;
  }
}

// ---------------- gate + x->bf16 conversion (fused) ----------------
__global__ void gate_kernel(const float* __restrict__ x, const float* __restrict__ Wg,
                            const float* __restrict__ bg,
                            int* __restrict__ topk_e, float* __restrict__ topk_w,
                            unsigned short* __restrict__ xb){
  const int t = blockIdx.x;
  const int lane = threadIdx.x;
  const float* xr = x + (size_t)t * DDIM;
  unsigned short* xbr = xb + (size_t)t * DDIM;
  float acc[NEXP];
  #pragma unroll
  for (int e = 0; e < NEXP; ++e) acc[e] = 0.f;
  #pragma unroll 4
  for (int it = 0; it < DDIM/64; ++it){
    int i = it*64 + lane;
    float xi = xr[i];
    xbr[i] = f2b(xi);
    const float4* wr = (const float4*)(Wg + (size_t)i * NEXP);
    float4 w0 = wr[0], w1 = wr[1];
    acc[0] += xi*w0.x; acc[1] += xi*w0.y; acc[2] += xi*w0.z; acc[3] += xi*w0.w;
    acc[4] += xi*w1.x; acc[5] += xi*w1.y; acc[6] += xi*w1.z; acc[7] += xi*w1.w;
  }
  #pragma unroll
  for (int e = 0; e < NEXP; ++e){
    float v = acc[e];
    #pragma unroll
    for (int off = 32; off > 0; off >>= 1) v += __shfl_xor(v, off, 64);
    acc[e] = v;
  }
  if (lane == 0){
    float l[NEXP], m = -1e30f;
    #pragma unroll
    for (int e = 0; e < NEXP; ++e){ l[e] = acc[e] + bg[e]; m = fmaxf(m, l[e]); }
    float p[NEXP], s = 0.f;
    #pragma unroll
    for (int e = 0; e < NEXP; ++e){ p[e] = expf(l[e] - m); s += p[e]; }
    float inv = 1.f / s;
    int a1 = 0; float v1 = -1.f;
    #pragma unroll
    for (int e = 0; e < NEXP; ++e){ p[e] *= inv; if (p[e] > v1){ v1 = p[e]; a1 = e; } }
    int a2 = -1; float v2 = -1.f;
    #pragma unroll
    for (int e = 0; e < NEXP; ++e){ if (e == a1) continue; if (p[e] > v2){ v2 = p[e]; a2 = e; } }
    topk_e[2*t]   = a1; topk_w[2*t]   = v1;
    topk_e[2*t+1] = a2; topk_w[2*t+1] = v2;
  }
}

// ---------------- route body: per-expert ordered compaction ----------------
__device__ __forceinline__ void route_body(const int* __restrict__ topk_e,
                                           const float* __restrict__ topk_w,
                                           int* __restrict__ expertList,
                                           float* __restrict__ pairW,
                                           int* __restrict__ counts,
                                           int e, int tid, int* pfx, int* base_s){
  if (tid == 0) *base_s = 0;
  __syncthreads();
  for (int c = 0; c < T_TOK/256; ++c){
    int t = c*256 + tid;
    int e0 = topk_e[2*t], e1 = topk_e[2*t+1];
    int sel = 0; float w = 0.f;
    if (e0 == e){ sel = 1; w = topk_w[2*t]; }
    else if (e1 == e){ sel = 1; w = topk_w[2*t+1]; }
    pfx[tid] = sel;
    __syncthreads();
    for (int off = 1; off < 256; off <<= 1){
      int v = (tid >= off) ? pfx[tid - off] : 0;
      __syncthreads();
      pfx[tid] += v;
      __syncthreads();
    }
    if (sel){
      int pos = *base_s + pfx[tid] - 1;
      expertList[e*T_TOK + pos] = t;
      pairW[e*T_TOK + pos] = w;
    }
    __syncthreads();
    if (tid == 0) *base_s += pfx[255];
    __syncthreads();
  }
  if (tid == 0) counts[e] = *base_s;
}

__device__ __forceinline__ void plan_body(const int* __restrict__ counts,
                                          int* __restrict__ nTiles,
                                          int* __restrict__ tileExpert,
                                          int* __restrict__ tileStart){
  int nt = 0;
  for (int e = 0; e < NEXP; ++e){
    int c = counts[e];
    int tcount = (c + 127) >> 7;
    for (int i = 0; i < tcount; ++i){ tileExpert[nt] = e; tileStart[nt] = i*128; ++nt; }
  }
  *nTiles = nt;
}

__global__ __launch_bounds__(256)
void route_count(const int* __restrict__ topk_e, const float* __restrict__ topk_w,
                 int* __restrict__ expertList, float* __restrict__ pairW,
                 int* __restrict__ counts){
  __shared__ int pfx[256];
  __shared__ int base_s;
  route_body(topk_e, topk_w, expertList, pairW, counts, blockIdx.x, threadIdx.x, pfx, &base_s);
}

// fused: blocks 0..7 route (+last-arriving block runs plan); blocks 8.. transpose W1
__global__ __launch_bounds__(256)
void route_t1_plan_fused(const int* __restrict__ topk_e, const float* __restrict__ topk_w,
                         int* __restrict__ expertList, float* __restrict__ pairW,
                         int* __restrict__ counts,
                         int* __restrict__ done,            // zeroed each call
                         int* __restrict__ nTiles,
                         int* __restrict__ tileExpert, int* __restrict__ tileStart,
                         const float* __restrict__ W1, unsigned short* __restrict__ W1t){
  __shared__ __align__(16) unsigned char smem[9216];
  if (blockIdx.x < NEXP){
    int* pfx = (int*)smem;
    int* base_s = (int*)(smem + 1024);
    route_body(topk_e, topk_w, expertList, pairW, counts, blockIdx.x, threadIdx.x, pfx, base_s);
    if (threadIdx.x == 0){
      __threadfence();                                  // counts[e] visible device-wide
      int prev = atomicAdd(done, 1);
      if (prev == NEXP - 1){                            // last route block: run plan inline
        __threadfence();                                // acquire all counts[]
        plan_body(counts, nTiles, tileExpert, tileStart);
      }
    }
  } else {
    transpose_body(W1, W1t, DDIM, HDIM, blockIdx.x - NEXP, threadIdx.x,
                   (unsigned short (*)[72])smem);
  }
}

__global__ void plan_kernel(const int* __restrict__ counts, int* __restrict__ nTiles,
                            int* __restrict__ tileExpert, int* __restrict__ tileStart){
  if (blockIdx.x != 0 || threadIdx.x != 0) return;
  plan_body(counts, nTiles, tileExpert, tileStart);
}

// ---------------- standalone transpose kernel (fallback path) ----------------
__global__ __launch_bounds__(256)
void transpose_w(const float* __restrict__ W, unsigned short* __restrict__ Wt,
                 int K, int N){
  __shared__ unsigned short t[64][72];
  const int bid = blockIdx.x + blockIdx.y*gridDim.x + blockIdx.z*gridDim.x*gridDim.y;
  transpose_body(W, Wt, K, N, bid, threadIdx.x, t);
}

// ------- grouped GEMM (session best): 128x128, BK=32, 4 waves, dbuf,
// 4 blocks/CU, top-placed counted vmcnt(4), T2 involution swizzle,
// n0-fastest decode + bijective XCD swizzle. -------
template<int LAYER, int KS>
__global__ __launch_bounds__(256, 4)
void moe_gemm(const unsigned short* __restrict__ Abf,
              const unsigned short* __restrict__ Wt,
              const float* __restrict__ bias,
              const int* __restrict__ nTilesPtr,
              const int* __restrict__ tileExpert,
              const int* __restrict__ tileStart,
              const int* __restrict__ counts,
              const int* __restrict__ expertList,
              const float* __restrict__ pairW,
              unsigned short* __restrict__ Hout,
              float* __restrict__ out)
{
  constexpr int KD = (LAYER == 1) ? DDIM : HDIM;
  constexpr int ND = (LAYER == 1) ? HDIM : DDIM;
  constexpr int NB = ND / 128;
  constexpr int NTfull = KD / 32;

  const int nwg = gridDim.x;
  const int b   = blockIdx.x;
  const int q8 = nwg >> 3, r8 = nwg & 7;
  const int xcd = b & 7, ii = b >> 3;
  const int lin = (xcd < r8 ? xcd*(q8+1) : r8*(q8+1) + (xcd-r8)*q8) + ii;
  const int tile = lin / NB;
  const int n0   = (lin % NB) * 128;
  const int kz   = blockIdx.y;

  if (tile >= *nTilesPtr) return;
  const int e   = tileExpert[tile];
  const int ts  = tileStart[tile];
  const int cnt = counts[e];
  const int tid  = threadIdx.x;
  const int lane = tid & 63;
  const int wave = tid >> 6;
  const int wm = (wave >> 1) * 64;
  const int wn = (wave & 1) * 64;

  __shared__ __align__(16) unsigned short As[2][128][32];
  __shared__ __align__(16) unsigned short Bs[2][128][32];
  __shared__ int   tokenBuf[128];
  __shared__ float wBuf[128];

  if (tid < 128){
    int pos = ts + tid;
    int tok = 0; float w = 0.f;
    if (pos < cnt){ tok = expertList[e*T_TOK + pos]; w = pairW[e*T_TOK + pos]; }
    tokenBuf[tid] = tok; wBuf[tid] = w;
  }
  __syncthreads();

  const int srow = tid >> 2;
  const int slot = (tid & 3) ^ ((tid >> 3) & 3);
  const int koff = slot * 8;
  const unsigned short* gA[2];
  const unsigned short* gB[2];
  #pragma unroll
  for (int g = 0; g < 2; ++g){
    const int row = g*64 + srow;
    if (LAYER == 1) gA[g] = Abf + (size_t)tokenBuf[row]*DDIM + koff;
    else            gA[g] = Abf + (size_t)(tile*128 + row)*HDIM + koff;
    gB[g] = Wt + ((size_t)e*ND + n0 + row)*KD + koff;
  }

  auto STAGE = [&](int buf, int ko){
    unsigned short* la = &As[buf][wave*16][0];
    unsigned short* lb = &Bs[buf][wave*16][0];
    #pragma unroll
    for (int g = 0; g < 2; ++g){
      GLOAD16(gA[g] + ko, la + g*2048);
      GLOAD16(gB[g] + ko, lb + g*2048);
    }
  };

  f32x4t acc[4][4] = {};
  const int fr = lane & 15;
  const int fq = lane >> 4;

  const int kt0 = (kz * NTfull) / KS;
  const int kt1 = ((kz + 1) * NTfull) / KS;
  const int NTl = kt1 - kt0;

  STAGE(0, kt0*32);

  int cur = 0;
  for (int t = 0; t < NTl; ++t){
    if (t + 1 < NTl){
      STAGE(cur ^ 1, (kt0 + t + 1)*32);
      SB0; asm volatile("s_waitcnt vmcnt(4)" ::: "memory");
    } else {
      SB0; asm volatile("s_waitcnt vmcnt(0)" ::: "memory");
    }
    __builtin_amdgcn_s_barrier();
    SB0;

    const unsigned short* Ab = &As[cur][0][0];
    const unsigned short* Bb = &Bs[cur][0][0];
    s16x8 bfr[4], afr[4];
    #pragma unroll
    for (int nf = 0; nf < 4; ++nf) bfr[nf] = lds_frag(Bb, wn + nf*16 + fr, fq*8);
    #pragma unroll
    for (int mf = 0; mf < 4; ++mf) afr[mf] = lds_frag(Ab, wm + mf*16 + fr, fq*8);
    #pragma unroll
    for (int mf = 0; mf < 4; ++mf)
      #pragma unroll
      for (int nf = 0; nf < 4; ++nf)
        acc[mf][nf] = __builtin_amdgcn_mfma_f32_16x16x32_bf16(afr[mf], bfr[nf], acc[mf][nf], 0, 0, 0);

    SB0;
    __builtin_amdgcn_s_barrier();
    SB0;
    cur ^= 1;
  }

  const int rbase = wm + fq*4;
  const int cbase = wn + fr;
  if (LAYER == 1){
    #pragma unroll
    for (int mf = 0; mf < 4; ++mf){
      #pragma unroll
      for (int nf = 0; nf < 4; ++nf){
        int c = cbase + nf*16;
        float bsv = bias[e*HDIM + n0 + c];
        #pragma unroll
        for (int j = 0; j < 4; ++j){
          int rr = rbase + mf*16 + j;
          float v = fmaxf(acc[mf][nf][j] + bsv, 0.f);
          __builtin_nontemporal_store((unsigned short)f2b(v),
              &Hout[(size_t)(tile*128 + rr)*HDIM + n0 + c]);
        }
      }
    }
  } else {
    #pragma unroll
    for (int mf = 0; mf < 4; ++mf){
      #pragma unroll
      for (int j = 0; j < 4; ++j){
        int rr = rbase + mf*16 + j;
        if (ts + rr < cnt){
          int tok = tokenBuf[rr];
          float w = wBuf[rr];
          #pragma unroll
          for (int nf = 0; nf < 4; ++nf){
            int c = cbase + nf*16;
            float v = acc[mf][nf][j];
            if (kz == 0) v += bias[e*DDIM + n0 + c];
            atomicAdd(out + (size_t)tok*DDIM + n0 + c, w * v);
          }
        }
      }
    }
  }
}

// ------- fused GEMM1 + transpose(W2): blocks [0,G1_NWG) = GEMM1; rest transpose -------
__global__ __launch_bounds__(256, 4)
void gemm1_t2_fused(const unsigned short* __restrict__ Abf,
                    const unsigned short* __restrict__ Wt,     // W1t
                    const float* __restrict__ bias,            // b1
                    const int* __restrict__ nTilesPtr,
                    const int* __restrict__ tileExpert,
                    const int* __restrict__ tileStart,
                    const int* __restrict__ counts,
                    const int* __restrict__ expertList,
                    unsigned short* __restrict__ Hout,
                    const float* __restrict__ W2,
                    unsigned short* __restrict__ W2t)
{
  __shared__ __align__(16) unsigned char smem[33792];
  if (blockIdx.x >= G1_NWG){
    transpose_body(W2, W2t, HDIM, DDIM, blockIdx.x - G1_NWG, threadIdx.x,
                   (unsigned short (*)[72])smem);
    return;
  }
  auto As = (unsigned short (*)[128][32])smem;
  auto Bs = (unsigned short (*)[128][32])(smem + 16384);
  int* tokenBuf = (int*)(smem + 32768);

  constexpr int KD = DDIM, ND = HDIM;
  constexpr int NB = ND / 128;
  constexpr int NT = KD / 32;

  const int nwg = G1_NWG;
  const int b   = blockIdx.x;
  const int q8 = nwg >> 3, r8 = nwg & 7;
  const int xcd = b & 7, ii = b >> 3;
  const int lin = (xcd < r8 ? xcd*(q8+1) : r8*(q8+1) + (xcd-r8)*q8) + ii;
  const int tile = lin / NB;
  const int n0   = (lin % NB) * 128;

  if (tile >= *nTilesPtr) return;
  const int e   = tileExpert[tile];
  const int ts  = tileStart[tile];
  const int cnt = counts[e];
  const int tid  = threadIdx.x;
  const int lane = tid & 63;
  const int wave = tid >> 6;
  const int wm = (wave >> 1) * 64;
  const int wn = (wave & 1) * 64;

  if (tid < 128){
    int pos = ts + tid;
    int tok = 0;
    if (pos < cnt) tok = expertList[e*T_TOK + pos];
    tokenBuf[tid] = tok;
  }
  __syncthreads();

  const int srow = tid >> 2;
  const int slot = (tid & 3) ^ ((tid >> 3) & 3);
  const int koff = slot * 8;
  const unsigned short* gA[2];
  const unsigned short* gB[2];
  #pragma unroll
  for (int g = 0; g < 2; ++g){
    const int row = g*64 + srow;
    gA[g] = Abf + (size_t)tokenBuf[row]*DDIM + koff;
    gB[g] = Wt + ((size_t)e*ND + n0 + row)*KD + koff;
  }

  auto STAGE = [&](int buf, int ko){
    unsigned short* la = &As[buf][wave*16][0];
    unsigned short* lb = &Bs[buf][wave*16][0];
    #pragma unroll
    for (int g = 0; g < 2; ++g){
      GLOAD16(gA[g] + ko, la + g*2048);
      GLOAD16(gB[g] + ko, lb + g*2048);
    }
  };

  f32x4t acc[4][4] = {};
  const int fr = lane & 15;
  const int fq = lane >> 4;

  STAGE(0, 0);

  int cur = 0;
  for (int t = 0; t < NT; ++t){
    if (t + 1 < NT){
      STAGE(cur ^ 1, (t + 1)*32);
      SB0; asm volatile("s_waitcnt vmcnt(4)" ::: "memory");
    } else {
      SB0; asm volatile("s_waitcnt vmcnt(0)" ::: "memory");
    }
    __builtin_amdgcn_s_barrier();
    SB0;

    const unsigned short* Ab = &As[cur][0][0];
    const unsigned short* Bb = &Bs[cur][0][0];
    s16x8 bfr[4], afr[4];
    #pragma unroll
    for (int nf = 0; nf < 4; ++nf) bfr[nf] = lds_frag(Bb, wn + nf*16 + fr, fq*8);
    #pragma unroll
    for (int mf = 0; mf < 4; ++mf) afr[mf] = lds_frag(Ab, wm + mf*16 + fr, fq*8);
    #pragma unroll
    for (int mf = 0; mf < 4; ++mf)
      #pragma unroll
      for (int nf = 0; nf < 4; ++nf)
        acc[mf][nf] = __builtin_amdgcn_mfma_f32_16x16x32_bf16(afr[mf], bfr[nf], acc[mf][nf], 0, 0, 0);

    SB0;
    __builtin_amdgcn_s_barrier();
    SB0;
    cur ^= 1;
  }

  const int rbase = wm + fq*4;
  const int cbase = wn + fr;
  #pragma unroll
  for (int mf = 0; mf < 4; ++mf){
    #pragma unroll
    for (int nf = 0; nf < 4; ++nf){
      int c = cbase + nf*16;
      float bsv = bias[e*HDIM + n0 + c];
      #pragma unroll
      for (int j = 0; j < 4; ++j){
        int rr = rbase + mf*16 + j;
        float v = fmaxf(acc[mf][nf][j] + bsv, 0.f);
        __builtin_nontemporal_store((unsigned short)f2b(v),
            &Hout[(size_t)(tile*128 + rr)*HDIM + n0 + c]);
      }
    }
  }
}

extern "C" void kernel_launch(void* const* d_in, const int* in_sizes, int n_in,
                              void* d_out, int out_size, void* d_ws, size_t ws_size,
                              hipStream_t stream){
  const float* x  = (const float*)d_in[0];
  const float* Wg = (const float*)d_in[1];
  const float* bg = (const float*)d_in[2];
  const float* W1 = (const float*)d_in[3];
  const float* b1 = (const float*)d_in[4];
  const float* W2 = (const float*)d_in[5];
  const float* b2 = (const float*)d_in[6];
  float* out = (float*)d_out;

  const size_t WB = (size_t)NEXP*DDIM*HDIM*sizeof(unsigned short);
  const size_t HB = (size_t)MAXTILES*128*HDIM*sizeof(unsigned short);

  char* p = (char*)d_ws;
  int*   topk_e     = (int*)p;   p += (size_t)T_TOK*2*sizeof(int);
  float* topk_w     = (float*)p; p += (size_t)T_TOK*2*sizeof(float);
  int*   counts     = (int*)p;   p += 8*sizeof(int);
  int*   nTiles     = (int*)p;   p += 8*sizeof(int);
  int*   done       = (int*)p;   p += 8*sizeof(int);
  int*   tileExpert = (int*)p;   p += 128*sizeof(int);
  int*   tileStart  = (int*)p;   p += 128*sizeof(int);
  int*   expertList = (int*)p;   p += (size_t)NEXP*T_TOK*sizeof(int);
  float* pairW      = (float*)p; p += (size_t)NEXP*T_TOK*sizeof(float);
  p = (char*)(((uintptr_t)p + 255) & ~(uintptr_t)255);
  unsigned short* xb = (unsigned short*)p;
  p += (size_t)T_TOK*DDIM*sizeof(unsigned short);
  p = (char*)(((uintptr_t)p + 255) & ~(uintptr_t)255);
  unsigned short* W1t = (unsigned short*)p; p += WB;
  p = (char*)(((uintptr_t)p + 255) & ~(uintptr_t)255);

  const size_t used = (size_t)(p - (char*)d_ws);
  const bool sep = (used + WB + 256 + HB + 256) <= ws_size;
  unsigned short* W2t;
  if (sep){
    W2t = (unsigned short*)p; p += WB;
    p = (char*)(((uintptr_t)p + 255) & ~(uintptr_t)255);
  } else {
    W2t = W1t;
  }
  unsigned short* Hact = (unsigned short*)p;

  hipMemsetAsync(d_out, 0, (size_t)T_TOK*DDIM*sizeof(float), stream);
  hipMemsetAsync(done, 0, sizeof(int), stream);
  gate_kernel<<<T_TOK, 64, 0, stream>>>(x, Wg, bg, topk_e, topk_w, xb);

  if (sep){
    // route + plan(last-block) + transpose(W1) in one dispatch; T2 hides under GEMM1
    route_t1_plan_fused<<<NEXP + TW_NWG, 256, 0, stream>>>(
        topk_e, topk_w, expertList, pairW, counts, done,
        nTiles, tileExpert, tileStart, W1, W1t);
    gemm1_t2_fused<<<G1_NWG + TW_NWG, 256, 0, stream>>>(
        xb, W1t, b1, nTiles, tileExpert, tileStart, counts, expertList, Hact, W2, W2t);
    moe_gemm<2,2><<<dim3(MAXTILES*(DDIM/128), 2), 256, 0, stream>>>(
        Hact, W2t, b2, nTiles, tileExpert, tileStart, counts, expertList, pairW, nullptr, out);
  } else {
    route_count<<<NEXP, 256, 0, stream>>>(topk_e, topk_w, expertList, pairW, counts);
    plan_kernel<<<1, 1, 0, stream>>>(counts, nTiles, tileExpert, tileStart);
    transpose_w<<<dim3(HDIM/64, DDIM/64, NEXP), 256, 0, stream>>>(W1, W1t, DDIM, HDIM);
    moe_gemm<1,1><<<dim3(G1_NWG, 1), 256, 0, stream>>>(
        xb, W1t, b1, nTiles, tileExpert, tileStart, counts, expertList, pairW, Hact, nullptr);
    transpose_w<<<dim3(DDIM/64, HDIM/64, NEXP), 256, 0, stream>>>(W2, W1t, HDIM, DDIM);
    moe_gemm<2,2><<<dim3(MAXTILES*(DDIM/128), 2), 256, 0, stream>>>(
        Hact, W1t, b2, nTiles, tileExpert, tileStart, counts, expertList, pairW, nullptr, out);
  }
}